// Round 3
// baseline (210.344 us; speedup 1.0000x reference)
//
#include <hip/hip_runtime.h>
#include <hip/hip_bf16.h>

// out[b, p, c, d, e] = sr * cos(phi[b]*p) - si * sin(phi[b]*p)
// B=8, C=40; p-stride C^3 = 64,000; batch stride C^4 = 2,560,000.
// R2 post-mortem: 75us kernel @ 3.26 TB/s logical (52% of achievable) —
// latency-bound on the per-thread sincosf chain with only 2 loads in flight.
// R3: (a) precompute the 320 (cos,sin) pairs into d_ws (kills the trig chain),
//     (b) 4 grid-strided float4 groups per thread (8 loads in flight),
//     (c) non-temporal output stores (output never re-read; keep L3 for inputs).

#define NBATCH 8
#define CUTOFF 40
#define C3 (CUTOFF * CUTOFF * CUTOFF)          // 64000  (divisible by 4)
#define C4 (C3 * CUTOFF)                       // 2560000
#define NTAB (NBATCH * CUTOFF)                 // 320

typedef float v4f __attribute__((ext_vector_type(4)));
typedef float v2f __attribute__((ext_vector_type(2)));

__global__ void build_phase_table(const float* __restrict__ phi,
                                  v2f* __restrict__ tab) {
    int t = threadIdx.x;                       // one block of 320 threads
    if (t < NTAB) {
        int b = t / CUTOFF;
        int p = t - b * CUTOFF;
        float s, c;
        sincosf(phi[b] * (float)p, &s, &c);
        v2f sc; sc.x = c; sc.y = s;
        tab[t] = sc;
    }
}

__global__ __launch_bounds__(256) void phase_apply(
    const float* __restrict__ sr,
    const float* __restrict__ si,
    const v2f* __restrict__ tab,
    float* __restrict__ out,
    int n4, int stride)                        // stride = total thread count
{
    int i = blockIdx.x * blockDim.x + threadIdx.x;

    const v4f* re4 = (const v4f*)sr;
    const v4f* im4 = (const v4f*)si;
    v4f*       o4  = (v4f*)out;

#pragma unroll
    for (int k = 0; k < 4; ++k) {
        int idx = i + k * stride;
        if (idx < n4) {
            int base = idx * 4;                // first complex elem of group
            int b    = base / C4;
            int rem  = base - b * C4;
            int p    = rem / C3;               // wave-uniform almost always

            v2f sc = tab[b * CUTOFF + p];      // (cos, sin) — L2-hit broadcast
            v4f re = re4[idx];
            v4f im = im4[idx];

            v4f o = re * sc.x - im * sc.y;
            __builtin_nontemporal_store(o, &o4[idx]);
        }
    }
}

extern "C" void kernel_launch(void* const* d_in, const int* in_sizes, int n_in,
                              void* d_out, int out_size, void* d_ws, size_t ws_size,
                              hipStream_t stream) {
    const float* phi = (const float*)d_in[0];
    const float* sr  = (const float*)d_in[1];
    const float* si  = (const float*)d_in[2];
    float* out = (float*)d_out;
    v2f*   tab = (v2f*)d_ws;

    int n  = in_sizes[1];                      // 20,480,000 complex elements
    int n4 = n / 4;                            // 5,120,000 float4 groups

    build_phase_table<<<1, 320, 0, stream>>>(phi, tab);

    int block   = 256;
    int threads = (n4 + 3) / 4;                // 4 groups per thread
    int grid    = (threads + block - 1) / block;
    int stride  = grid * block;
    phase_apply<<<grid, block, 0, stream>>>(sr, si, tab, out, n4, stride);
}

// Round 4
// 210.151 us; speedup vs baseline: 1.0009x; 1.0009x over previous
//
#include <hip/hip_runtime.h>
#include <hip/hip_bf16.h>

// out[b, p, c, d, e] = sr * cos(phi[b]*p) - si * sin(phi[b]*p)
// B=8, C=40; p-stride C^3 = 64,000; batch stride C^4 = 2,560,000.
//
// R3 post-mortem: VGPR_Count=8 proved the compiler serialized the "ILP" loop
// (a float4 load needs 4 VGPRs; 8 total = ~2 loads in flight). Both R2 and R3
// sat at the same ~3.2 TB/s logical wall -> latency x outstanding-lines bound,
// with sr DRAM-cold (~900 cy). R4: force 16 independent dwordx4 loads into
// registers per wave iteration (8 sweeps/block, no guards), coefficient via
// wave-uniform readfirstlane -> scalar constant-cache load.

#define NBATCH 8
#define CUTOFF 40
#define C3 (CUTOFF * CUTOFF * CUTOFF)          // 64000
#define C4 (C3 * CUTOFF)                       // 2560000
#define NTAB (NBATCH * CUTOFF)                 // 320
#define SWEEPS 8
#define GPB (SWEEPS * 256)                     // float4 groups per block = 2048

typedef float v4f __attribute__((ext_vector_type(4)));
typedef float v2f __attribute__((ext_vector_type(2)));

__global__ void build_phase_table(const float* __restrict__ phi,
                                  v2f* __restrict__ tab) {
    int t = threadIdx.x;                       // one block of 320 threads
    if (t < NTAB) {
        int b = t / CUTOFF;
        int p = t - b * CUTOFF;
        float s, c;
        sincosf(phi[b] * (float)p, &s, &c);
        v2f sc; sc.x = c; sc.y = s;
        tab[t] = sc;
    }
}

__global__ __launch_bounds__(256) void phase_apply(
    const float* __restrict__ sr,
    const float* __restrict__ si,
    const v2f* __restrict__ tab,
    float* __restrict__ out)
{
    int t = blockIdx.x * GPB + threadIdx.x;    // sweep-0 group index

    const v4f* re4 = (const v4f*)sr;
    const v4f* im4 = (const v4f*)si;
    v4f*       o4  = (v4f*)out;

    // Batch ALL loads first: 16 independent global_load_dwordx4 in flight.
    v4f re[SWEEPS], im[SWEEPS];
#pragma unroll
    for (int k = 0; k < SWEEPS; ++k) {
        re[k] = re4[t + k * 256];
        im[k] = im4[t + k * 256];
    }

#pragma unroll
    for (int k = 0; k < SWEEPS; ++k) {
        int idx  = t + k * 256;
        int base = idx * 4;
        int b    = base / C4;
        int p    = (base - b * C4) / C3;
        // wave spans 256 consecutive elems; C3 % 256 == 0 -> (b,p) wave-uniform
        int ti   = __builtin_amdgcn_readfirstlane(b * CUTOFF + p);
        v2f sc   = tab[ti];                    // scalar (constant-cache) load
        v4f o    = re[k] * sc.x - im[k] * sc.y;
        __builtin_nontemporal_store(o, &o4[idx]);
    }
}

// guarded scalar-ish tail (only launched if n4 % GPB != 0; not hit for B=8,C=40)
__global__ __launch_bounds__(256) void phase_apply_tail(
    const float* __restrict__ sr,
    const float* __restrict__ si,
    const v2f* __restrict__ tab,
    float* __restrict__ out,
    int start, int n4)
{
    int idx = start + blockIdx.x * blockDim.x + threadIdx.x;
    if (idx >= n4) return;
    int base = idx * 4;
    int b    = base / C4;
    int p    = (base - b * C4) / C3;
    v2f sc   = tab[b * CUTOFF + p];
    const v4f re = ((const v4f*)sr)[idx];
    const v4f im = ((const v4f*)si)[idx];
    v4f o = re * sc.x - im * sc.y;
    ((v4f*)out)[idx] = o;
}

extern "C" void kernel_launch(void* const* d_in, const int* in_sizes, int n_in,
                              void* d_out, int out_size, void* d_ws, size_t ws_size,
                              hipStream_t stream) {
    const float* phi = (const float*)d_in[0];
    const float* sr  = (const float*)d_in[1];
    const float* si  = (const float*)d_in[2];
    float* out = (float*)d_out;
    v2f*   tab = (v2f*)d_ws;

    int n  = in_sizes[1];                      // 20,480,000 complex elements
    int n4 = n / 4;                            // 5,120,000 float4 groups

    build_phase_table<<<1, 320, 0, stream>>>(phi, tab);

    int nblocks = n4 / GPB;                    // 2500 for this problem
    if (nblocks > 0)
        phase_apply<<<nblocks, 256, 0, stream>>>(sr, si, tab, out);

    int rem_start = nblocks * GPB;
    int rem = n4 - rem_start;
    if (rem > 0) {
        int grid = (rem + 255) / 256;
        phase_apply_tail<<<grid, 256, 0, stream>>>(sr, si, tab, out, rem_start, n4);
    }
}

// Round 5
// 191.191 us; speedup vs baseline: 1.1002x; 1.0992x over previous
//
#include <hip/hip_runtime.h>
#include <hip/hip_bf16.h>

// out[b, p, c, d, e] = sr * cos(phi[b]*p) - si * sin(phi[b]*p)
// B=8, C=40; p-stride C^3 = 64,000; batch stride C^4 = 2,560,000.
//
// R4 post-mortem: three structurally different kernels (R2/R3/R4) all land at
// 75-76 us -> per-wave MLP falsified as bottleneck. Model: harness restore+
// poison leaves ~244 MB dirty in the 256-MB L3; our reads allocating into L3
// evict dirty lines -> hidden DRAM writebacks (invisible to TCC WRITE_SIZE)
// eat ~half the DRAM bandwidth in our window. R5: nontemporal LOADS (evict-
// first, don't displace dirty lines) + nontemporal stores; sincos folded back
// in (wave-uniform (b,p)) to drop the table dispatch (~6 us bench-level).

#define NBATCH 8
#define CUTOFF 40
#define C3 (CUTOFF * CUTOFF * CUTOFF)          // 64000
#define C4 (C3 * CUTOFF)                       // 2560000
#define SWEEPS 8
#define GPB (SWEEPS * 256)                     // float4 groups per block = 2048

typedef float v4f __attribute__((ext_vector_type(4)));

__global__ __launch_bounds__(256) void phase_apply(
    const float* __restrict__ phi,
    const float* __restrict__ sr,
    const float* __restrict__ si,
    float* __restrict__ out)
{
    int t = blockIdx.x * GPB + threadIdx.x;    // sweep-0 group index

    const v4f* re4 = (const v4f*)sr;
    const v4f* im4 = (const v4f*)si;
    v4f*       o4  = (v4f*)out;

    // Batch all 16 loads, nontemporal: stream through L2/L3 without
    // displacing the harness's dirty restore lines.
    v4f re[SWEEPS], im[SWEEPS];
#pragma unroll
    for (int k = 0; k < SWEEPS; ++k) {
        re[k] = __builtin_nontemporal_load(&re4[t + k * 256]);
        im[k] = __builtin_nontemporal_load(&im4[t + k * 256]);
    }

#pragma unroll
    for (int k = 0; k < SWEEPS; ++k) {
        int idx  = t + k * 256;
        int base = idx * 4;
        int b    = base / C4;
        int p    = (base - b * C4) / C3;
        // wave spans 256 consecutive elems; C3 % 256 == 0 -> (b,p) wave-uniform
        int bu = __builtin_amdgcn_readfirstlane(b);
        int pu = __builtin_amdgcn_readfirstlane(p);
        float s, c;
        sincosf(phi[bu] * (float)pu, &s, &c);   // ~8 sincos/thread: VALU noise
        v4f o = re[k] * c - im[k] * s;
        __builtin_nontemporal_store(o, &o4[idx]);
    }
}

// guarded tail (not hit for B=8, C=40: n4 % GPB == 0), kept for generality
__global__ __launch_bounds__(256) void phase_apply_tail(
    const float* __restrict__ phi,
    const float* __restrict__ sr,
    const float* __restrict__ si,
    float* __restrict__ out,
    int start, int n4)
{
    int idx = start + blockIdx.x * blockDim.x + threadIdx.x;
    if (idx >= n4) return;
    int base = idx * 4;
    int b    = base / C4;
    int p    = (base - b * C4) / C3;
    float s, c;
    sincosf(phi[b] * (float)p, &s, &c);
    const v4f re = ((const v4f*)sr)[idx];
    const v4f im = ((const v4f*)si)[idx];
    v4f o = re * c - im * s;
    ((v4f*)out)[idx] = o;
}

extern "C" void kernel_launch(void* const* d_in, const int* in_sizes, int n_in,
                              void* d_out, int out_size, void* d_ws, size_t ws_size,
                              hipStream_t stream) {
    const float* phi = (const float*)d_in[0];
    const float* sr  = (const float*)d_in[1];
    const float* si  = (const float*)d_in[2];
    float* out = (float*)d_out;

    int n  = in_sizes[1];                      // 20,480,000 complex elements
    int n4 = n / 4;                            // 5,120,000 float4 groups

    int nblocks = n4 / GPB;                    // 2500 for this problem
    if (nblocks > 0)
        phase_apply<<<nblocks, 256, 0, stream>>>(phi, sr, si, out);

    int rem_start = nblocks * GPB;
    int rem = n4 - rem_start;
    if (rem > 0) {
        int grid = (rem + 255) / 256;
        phase_apply_tail<<<grid, 256, 0, stream>>>(phi, sr, si, out, rem_start, n4);
    }
}